// Round 14
// baseline (914.021 us; speedup 1.0000x reference)
//
#include <hip/hip_runtime.h>
#include <hip/hip_bf16.h>

typedef __attribute__((ext_vector_type(8))) short s16x8;
typedef __attribute__((ext_vector_type(4))) short s16x4;
typedef __attribute__((ext_vector_type(4))) float f32x4;

#define GAS __attribute__((address_space(1)))
#define LAS __attribute__((address_space(3)))

#define WAITL() asm volatile("s_waitcnt lgkmcnt(0)" ::: "memory")

__device__ __forceinline__ float b2f(unsigned short u) {
  union { unsigned int i; float f; } x; x.i = ((unsigned int)u) << 16; return x.f;
}
__device__ __forceinline__ unsigned short f2b(float f) {
  union { float f; unsigned int i; } x; x.f = f;
  unsigned int r = x.i + 0x7fffu + ((x.i >> 16) & 1u);
  return (unsigned short)(r >> 16);
}

// async global->LDS, 16B per lane; lds dest is wave-uniform base + lane*16
__device__ __forceinline__ void gl16(const unsigned short* g, unsigned short* l) {
  __builtin_amdgcn_global_load_lds((const GAS unsigned int*)g,
                                   (LAS unsigned int*)l, 16, 0, 0);
}

// ---------------- packing ----------------
__global__ __launch_bounds__(256) void pack_x_k(const float* __restrict__ x,
                                                unsigned short* __restrict__ xb) {
  size_t i = ((size_t)blockIdx.x * 256 + threadIdx.x) * 8;
  f32x4 a = *(const f32x4*)(x + i);
  f32x4 b = *(const f32x4*)(x + i + 4);
  float vals[8] = {a.x, a.y, a.z, a.w, b.x, b.y, b.z, b.w};
  s16x8 o;
#pragma unroll
  for (int k = 0; k < 8; k++) o[k] = (short)f2b(vals[k]);
  *(s16x8*)(xb + i) = o;
}

__global__ __launch_bounds__(256) void pack_qkv_k(const float* __restrict__ wq,
                                                  const float* __restrict__ wk,
                                                  const float* __restrict__ wv,
                                                  unsigned short* __restrict__ dst) {
  int idx = blockIdx.x * 256 + threadIdx.x;   // n*512 + c
  int n = idx >> 9, c = idx & 511;
  int sel = n >> 9;
  int hn = n & 511;
  const float* src = sel == 0 ? wq : (sel == 1 ? wk : wv);
  float v = src[((hn >> 6) << 15) + (c << 6) + (hn & 63)];  // wq[h][c][d]
  dst[idx] = f2b(v);
}

// dst[n][k] = src[k][n], src is (K,N) row-major
__global__ __launch_bounds__(256) void pack_T_k(const float* __restrict__ src,
                                                unsigned short* __restrict__ dst,
                                                int K, int N) {
  int idx = blockIdx.x * 256 + threadIdx.x;
  int n = idx / K, k = idx % K;
  dst[idx] = f2b(src[(long long)k * N + n]);
}

// ---------------- layernorm (wave per row, C=512), fp32 input (fallback) ----------------
__global__ __launch_bounds__(256) void ln_k(const float* __restrict__ in,
                                            const float* __restrict__ g,
                                            const float* __restrict__ bb,
                                            unsigned short* __restrict__ out) {
  int row = blockIdx.x * 4 + (threadIdx.x >> 6);
  int lane = threadIdx.x & 63;
  const float* p = in + (size_t)row * 512 + lane * 8;
  f32x4 a = *(const f32x4*)p;
  f32x4 b = *(const f32x4*)(p + 4);
  float vals[8] = {a.x, a.y, a.z, a.w, b.x, b.y, b.z, b.w};
  float s = 0.f, q = 0.f;
#pragma unroll
  for (int i = 0; i < 8; i++) { s += vals[i]; q += vals[i] * vals[i]; }
#pragma unroll
  for (int off = 1; off < 64; off <<= 1) {
    s += __shfl_xor(s, off);
    q += __shfl_xor(q, off);
  }
  float mean = s * (1.0f / 512.0f);
  float rstd = rsqrtf(q * (1.0f / 512.0f) - mean * mean + 1e-5f);
  const float* gp = g + lane * 8;
  const float* bp = bb + lane * 8;
  s16x8 o;
#pragma unroll
  for (int i = 0; i < 8; i++) o[i] = (short)f2b((vals[i] - mean) * rstd * gp[i] + bp[i]);
  *(s16x8*)(out + (size_t)row * 512 + lane * 8) = o;
}

// ---------------- layernorm, bf16 input ----------------
__global__ __launch_bounds__(256) void ln_b_k(const unsigned short* __restrict__ in,
                                              const float* __restrict__ g,
                                              const float* __restrict__ bb,
                                              unsigned short* __restrict__ out) {
  int row = blockIdx.x * 4 + (threadIdx.x >> 6);
  int lane = threadIdx.x & 63;
  s16x8 v8 = *(const s16x8*)(in + (size_t)row * 512 + lane * 8);
  float vals[8];
#pragma unroll
  for (int i = 0; i < 8; i++) vals[i] = b2f((unsigned short)v8[i]);
  float s = 0.f, q = 0.f;
#pragma unroll
  for (int i = 0; i < 8; i++) { s += vals[i]; q += vals[i] * vals[i]; }
#pragma unroll
  for (int off = 1; off < 64; off <<= 1) {
    s += __shfl_xor(s, off);
    q += __shfl_xor(q, off);
  }
  float mean = s * (1.0f / 512.0f);
  float rstd = rsqrtf(q * (1.0f / 512.0f) - mean * mean + 1e-5f);
  const float* gp = g + lane * 8;
  const float* bp = bb + lane * 8;
  s16x8 o;
#pragma unroll
  for (int i = 0; i < 8; i++) o[i] = (short)f2b((vals[i] - mean) * rstd * gp[i] + bp[i]);
  *(s16x8*)(out + (size_t)row * 512 + lane * 8) = o;
}

// ---------------- attention (one wave per (b,h); T=16, D=64) ----------------
__global__ __launch_bounds__(256) void attn_k(const unsigned short* __restrict__ qkv,
                                              unsigned short* __restrict__ o) {
  int w = (blockIdx.x << 2) + (threadIdx.x >> 6);
  int lane = threadIdx.x & 63;
  int b = w >> 3, h = w & 7;
  int t = lane >> 2, p = lane & 3;   // 4 lanes per query row, 16 d's each

  size_t rowq = (size_t)(b * 16 + t) * 1536 + h * 64 + p * 16;
  float q[16];
  {
    s16x8 q0 = *(const s16x8*)(qkv + rowq);
    s16x8 q1 = *(const s16x8*)(qkv + rowq + 8);
#pragma unroll
    for (int i = 0; i < 8; i++) {
      q[i] = b2f((unsigned short)q0[i]) * 0.125f;
      q[8 + i] = b2f((unsigned short)q1[i]) * 0.125f;
    }
  }
  float lg[16];
  size_t kbase = (size_t)(b * 16) * 1536 + 512 + h * 64 + p * 16;
#pragma unroll
  for (int s = 0; s < 16; s++) {
    const unsigned short* kp = qkv + kbase + (size_t)s * 1536;
    s16x8 k0 = *(const s16x8*)kp;
    s16x8 k1 = *(const s16x8*)(kp + 8);
    float d = 0.f;
#pragma unroll
    for (int i = 0; i < 8; i++)
      d += q[i] * b2f((unsigned short)k0[i]) + q[8 + i] * b2f((unsigned short)k1[i]);
    d += __shfl_xor(d, 1);
    d += __shfl_xor(d, 2);
    lg[s] = d;
  }
  float mx = -1e30f;
#pragma unroll
  for (int s = 0; s < 16; s++)
    if (s <= t) mx = fmaxf(mx, lg[s]);
  float den = 0.f;
#pragma unroll
  for (int s = 0; s < 16; s++) {
    float e = (s <= t) ? __expf(lg[s] - mx) : 0.f;
    lg[s] = e;
    den += e;
  }
  float inv = 1.f / den;
  float acc[16] = {};
  size_t vbase = kbase + 512;
#pragma unroll
  for (int s = 0; s < 16; s++) {
    const unsigned short* vp = qkv + vbase + (size_t)s * 1536;
    s16x8 v0 = *(const s16x8*)vp;
    s16x8 v1 = *(const s16x8*)(vp + 8);
    float a = lg[s] * inv;
#pragma unroll
    for (int i = 0; i < 8; i++) {
      acc[i] += a * b2f((unsigned short)v0[i]);
      acc[8 + i] += a * b2f((unsigned short)v1[i]);
    }
  }
  size_t orow = (size_t)(b * 16 + t) * 512 + h * 64 + p * 16;
  s16x8 r0, r1;
#pragma unroll
  for (int i = 0; i < 8; i++) {
    r0[i] = (short)f2b(acc[i]);
    r1[i] = (short)f2b(acc[8 + i]);
  }
  *(s16x8*)(o + orow) = r0;
  *(s16x8*)(o + orow + 8) = r1;
}

// ---------------- bf16 MFMA GEMM: m97 structure (128x128, BK=32, 4 waves) ----------------
// Single 16KB LDS buffer, 2x __syncthreads per K-step; relies on ~3 blocks/CU
// overlapping each other's stalls (m97: 912 TF; m114: implicit cross-block
// overlap ~= explicit pipelining). Source-side XOR swizzle (0 conflicts
// verified r2-r13): LDS[r][p] = G[r][p ^ ((r>>1)&3)], read slot s4^((l15>>1)&3).
// bf16 epilogues: LDS-staged full-line short4 stores (kills 2.3x write amp).
enum { EPI_BF16 = 0, EPI_RESF32 = 1, EPI_RELU = 2, EPI_YBB = 3, EPI_OUTB = 4 };

template <int EPI>
__global__ __launch_bounds__(256) void gemm_bt(
    const unsigned short* __restrict__ A,   // (M, K) bf16
    const unsigned short* __restrict__ Bt,  // (N, K) bf16
    int K, int N, int nT,
    const float* __restrict__ bias, const void* __restrict__ res,
    float* __restrict__ outF, unsigned short* __restrict__ outB) {
  // staging: As [128][32] at 0 (8KB), Bs [128][32] at 8192 (8KB);
  // epilogue overlay: 4 waves x 16x68 fp32 = 17408 B
  __shared__ __align__(16) unsigned char SM[17408];
  unsigned short* As = (unsigned short*)SM;
  unsigned short* Bs = (unsigned short*)(SM + 8192);

  int tid = threadIdx.x;
  // XCD-chunked 1D swizzle, N-fastest tile order (grids are multiples of 8)
  int lid = ((int)blockIdx.x & 7) * ((int)gridDim.x >> 3) + ((int)blockIdx.x >> 3);
  int mBase = (lid / nT) * 128;
  int nBase = (lid % nT) * 128;

  int lane = tid & 63;
  int wv = tid >> 6;
  int wr = (wv >> 1) * 64, wc = (wv & 1) * 64;  // 2x2 wave grid, 64x64 each
  int l15 = lane & 15;
  int s4 = lane >> 4;
  int lr4 = s4 * 4;
  int fc = ((s4 ^ ((l15 >> 1) & 3)) << 3);  // swizzled 8-elem slot for ds_read

  // staging: thread covers row tid>>2 (0..63, +64 for 2nd chunk), 16B slot tid&3;
  // global source col pre-swizzled: LDS[r][p] = G[r][p ^ ((r>>1)&3)]
  int sr = tid >> 2;
  int gc = (((tid & 3) ^ ((tid >> 3) & 3)) << 3);
  const unsigned short* pa = A + (size_t)(mBase + sr) * K + gc;
  const unsigned short* pb = Bt + (size_t)(nBase + sr) * K + gc;
  unsigned short* lA = As + wv * 512;   // wave-uniform LDS bases (1024 B/wave)
  unsigned short* lB = Bs + wv * 512;
  size_t rowskip = (size_t)64 * K;

  f32x4 acc[4][4] = {};

  for (int kt = 0; kt < K; kt += 32) {
    __syncthreads();                       // previous iteration's reads done
    gl16(pa + kt, lA);                     // rows 0..63
    gl16(pa + kt + rowskip, lA + 2048);    // rows 64..127
    gl16(pb + kt, lB);
    gl16(pb + kt + rowskip, lB + 2048);
    __syncthreads();                       // drains vmcnt(0): loads landed
    s16x8 af[4], bf[4];
#pragma unroll
    for (int m = 0; m < 4; m++) af[m] = *(const s16x8*)&As[(wr + m * 16 + l15) * 32 + fc];
#pragma unroll
    for (int n = 0; n < 4; n++) bf[n] = *(const s16x8*)&Bs[(wc + n * 16 + l15) * 32 + fc];
#pragma unroll
    for (int m = 0; m < 4; m++)
#pragma unroll
      for (int n = 0; n < 4; n++)
        acc[m][n] = __builtin_amdgcn_mfma_f32_16x16x32_bf16(af[m], bf[n], acc[m][n], 0, 0, 0);
  }
  __syncthreads();   // safe to reuse LDS for epilogue staging

  if (EPI == EPI_RESF32 || EPI == EPI_OUTB) {
    // fp32 output: direct stores are full 64B lines (16 lanes x 4B x 4 rows)
#pragma unroll
    for (int n = 0; n < 4; n++) {
      int gc2 = nBase + wc + n * 16 + l15;
      float bv = bias[gc2];
#pragma unroll
      for (int m = 0; m < 4; m++) {
#pragma unroll
        for (int j = 0; j < 4; j++) {
          int gr = mBase + wr + m * 16 + lr4 + j;
          size_t off = (size_t)gr * N + gc2;
          float v = acc[m][n][j] + bv;
          if (EPI == EPI_RESF32)
            outF[off] = v + ((const float*)res)[off];
          else
            outF[off] = v + b2f(((const unsigned short*)res)[off]);
        }
      }
    }
  } else {
    // bf16 output: stage per-wave 16x64 fp32 in LDS, read back row-contiguous,
    // write short4 (16 lanes x 8B = 128B full-line runs per row)
    float* ep = (float*)SM + wv * 1088;   // 4352 B/wave, row stride 68 floats
    int colc = nBase + wc + l15 * 4;
    f32x4 bias4 = {0.f, 0.f, 0.f, 0.f};
    if (EPI != EPI_BF16) bias4 = *(const f32x4*)&bias[colc];
#pragma unroll
    for (int m = 0; m < 4; m++) {
#pragma unroll
      for (int n = 0; n < 4; n++)
#pragma unroll
        for (int j = 0; j < 4; j++)
          ep[(lr4 + j) * 68 + n * 16 + l15] = acc[m][n][j];
      WAITL();
#pragma unroll
      for (int rd = 0; rd < 4; rd++) {
        int r = s4 + 4 * rd;
        f32x4 v = *(const f32x4*)&ep[r * 68 + l15 * 4];
        v.x += bias4.x; v.y += bias4.y; v.z += bias4.z; v.w += bias4.w;
        int gr = mBase + wr + m * 16 + r;
        size_t off = (size_t)gr * N + colc;
        if (EPI == EPI_YBB) {
          s16x4 rb = *(const s16x4*)((const unsigned short*)res + off);
          v.x += b2f((unsigned short)rb[0]); v.y += b2f((unsigned short)rb[1]);
          v.z += b2f((unsigned short)rb[2]); v.w += b2f((unsigned short)rb[3]);
        } else if (EPI == EPI_RELU) {
          v.x = fmaxf(v.x, 0.f); v.y = fmaxf(v.y, 0.f);
          v.z = fmaxf(v.z, 0.f); v.w = fmaxf(v.w, 0.f);
        }
        s16x4 o;
        o[0] = (short)f2b(v.x); o[1] = (short)f2b(v.y);
        o[2] = (short)f2b(v.z); o[3] = (short)f2b(v.w);
        *(s16x4*)(outB + off) = o;
      }
      WAITL();  // reads of m done before m+1 overwrites (per-wave region)
    }
  }
}

// ---------------- launch ----------------
extern "C" void kernel_launch(void* const* d_in, const int* in_sizes, int n_in,
                              void* d_out, int out_size, void* d_ws, size_t ws_size,
                              hipStream_t stream) {
  const float* x      = (const float*)d_in[0];
  const float* ln1_g  = (const float*)d_in[1];
  const float* ln1_b  = (const float*)d_in[2];
  const float* wq     = (const float*)d_in[3];
  const float* wk     = (const float*)d_in[4];
  const float* wv     = (const float*)d_in[5];
  const float* w_proj = (const float*)d_in[6];
  const float* b_proj = (const float*)d_in[7];
  const float* ln2_g  = (const float*)d_in[8];
  const float* ln2_b  = (const float*)d_in[9];
  const float* w1     = (const float*)d_in[10];
  const float* b1     = (const float*)d_in[11];
  const float* w2     = (const float*)d_in[12];
  const float* b2     = (const float*)d_in[13];
  float* out = (float*)d_out;

  char* ws = (char*)d_ws;
  unsigned short* qkvT  = (unsigned short*)(ws + 0);          // 1.5 MB
  unsigned short* projT = (unsigned short*)(ws + 1572864);    // 0.5 MB
  unsigned short* w1T   = (unsigned short*)(ws + 2097152);    // 2 MB
  unsigned short* w2T   = (unsigned short*)(ws + 4194304);    // 2 MB
  unsigned short* hbuf  = (unsigned short*)(ws + 6291456);    // 67 MB (h, then h2)
  unsigned short* qkv   = (unsigned short*)(ws + 73400320);   // 201 MB of 268 MB region (ff)
  unsigned short* xb    = (unsigned short*)(ws + 274726912);  // 67 MB spare in ff region
  unsigned short* obuf  = (unsigned short*)(ws + 341835776);  // 67 MB
  unsigned short* ybuf  = (unsigned short*)(ws + 408944640);  // 67 MB (bf16 y) if room
  bool yb16 = ws_size >= 476053504ull;

  pack_qkv_k<<<3072, 256, 0, stream>>>(wq, wk, wv, qkvT);
  pack_T_k<<<1024, 256, 0, stream>>>(w_proj, projT, 512, 512);
  pack_T_k<<<4096, 256, 0, stream>>>(w1, w1T, 512, 2048);
  pack_T_k<<<4096, 256, 0, stream>>>(w2, w2T, 2048, 512);

  unsigned short* ff = qkv;  // ff (268 MB) overlays qkv+xb after both are dead
  if (yb16) {
    pack_x_k<<<16384, 256, 0, stream>>>(x, xb);         // x -> bf16 once
    ln_b_k<<<16384, 256, 0, stream>>>(xb, ln1_g, ln1_b, hbuf);
    // qkv = h @ [wq|wk|wv]  (M=65536, K=512, N=1536): 512 m x 12 n = 6144
    gemm_bt<EPI_BF16><<<6144, 256, 0, stream>>>(hbuf, qkvT, 512, 1536, 12,
                                                nullptr, nullptr, nullptr, qkv);
    attn_k<<<8192, 256, 0, stream>>>(qkv, obuf);
    // y(bf16) = o @ w_proj + b_proj + xb
    gemm_bt<EPI_YBB><<<2048, 256, 0, stream>>>(obuf, projT, 512, 512, 4,
                                               b_proj, xb, nullptr, ybuf);
    ln_b_k<<<16384, 256, 0, stream>>>(ybuf, ln2_g, ln2_b, hbuf);
    // ff = relu(h2 @ w1 + b1)  — overwrites qkv AND xb region (both dead)
    gemm_bt<EPI_RELU><<<8192, 256, 0, stream>>>(hbuf, w1T, 512, 2048, 16,
                                                b1, nullptr, nullptr, ff);
    // out(f32) = ff @ w2 + b2 + y(bf16)
    gemm_bt<EPI_OUTB><<<2048, 256, 0, stream>>>(ff, w2T, 2048, 512, 4,
                                                b2, ybuf, out, nullptr);
  } else {
    // fallback: y fp32 in d_out, no xb
    ln_k<<<16384, 256, 0, stream>>>(x, ln1_g, ln1_b, hbuf);
    gemm_bt<EPI_BF16><<<6144, 256, 0, stream>>>(hbuf, qkvT, 512, 1536, 12,
                                                nullptr, nullptr, nullptr, qkv);
    attn_k<<<8192, 256, 0, stream>>>(qkv, obuf);
    gemm_bt<EPI_RESF32><<<2048, 256, 0, stream>>>(obuf, projT, 512, 512, 4,
                                                  b_proj, x, out, nullptr);
    ln_k<<<16384, 256, 0, stream>>>(out, ln2_g, ln2_b, hbuf);
    gemm_bt<EPI_RELU><<<8192, 256, 0, stream>>>(hbuf, w1T, 512, 2048, 16,
                                                b1, nullptr, nullptr, ff);
    gemm_bt<EPI_RESF32><<<2048, 256, 0, stream>>>(ff, w2T, 2048, 512, 4,
                                                  b2, out, out, nullptr);
  }
}

// Round 15
// 760.347 us; speedup vs baseline: 1.2021x; 1.2021x over previous
//
#include <hip/hip_runtime.h>
#include <hip/hip_bf16.h>

typedef __attribute__((ext_vector_type(8))) short s16x8;
typedef __attribute__((ext_vector_type(4))) short s16x4;
typedef __attribute__((ext_vector_type(4))) float f32x4;

#define GAS __attribute__((address_space(1)))
#define LAS __attribute__((address_space(3)))

#define WAITV(N) asm volatile("s_waitcnt vmcnt(" #N ")" ::: "memory")
#define WAITL() asm volatile("s_waitcnt lgkmcnt(0)" ::: "memory")
#define BAR() __builtin_amdgcn_s_barrier()

__device__ __forceinline__ float b2f(unsigned short u) {
  union { unsigned int i; float f; } x; x.i = ((unsigned int)u) << 16; return x.f;
}
__device__ __forceinline__ unsigned short f2b(float f) {
  union { float f; unsigned int i; } x; x.f = f;
  unsigned int r = x.i + 0x7fffu + ((x.i >> 16) & 1u);
  return (unsigned short)(r >> 16);
}

// async global->LDS, 16B per lane; lds dest is wave-uniform base + lane*16
__device__ __forceinline__ void gl16(const unsigned short* g, unsigned short* l) {
  __builtin_amdgcn_global_load_lds((const GAS unsigned int*)g,
                                   (LAS unsigned int*)l, 16, 0, 0);
}

// ---------------- packing ----------------
__global__ __launch_bounds__(256) void pack_x_k(const float* __restrict__ x,
                                                unsigned short* __restrict__ xb) {
  size_t i = ((size_t)blockIdx.x * 256 + threadIdx.x) * 8;
  f32x4 a = *(const f32x4*)(x + i);
  f32x4 b = *(const f32x4*)(x + i + 4);
  float vals[8] = {a.x, a.y, a.z, a.w, b.x, b.y, b.z, b.w};
  s16x8 o;
#pragma unroll
  for (int k = 0; k < 8; k++) o[k] = (short)f2b(vals[k]);
  *(s16x8*)(xb + i) = o;
}

__global__ __launch_bounds__(256) void pack_qkv_k(const float* __restrict__ wq,
                                                  const float* __restrict__ wk,
                                                  const float* __restrict__ wv,
                                                  unsigned short* __restrict__ dst) {
  int idx = blockIdx.x * 256 + threadIdx.x;   // n*512 + c
  int n = idx >> 9, c = idx & 511;
  int sel = n >> 9;
  int hn = n & 511;
  const float* src = sel == 0 ? wq : (sel == 1 ? wk : wv);
  float v = src[((hn >> 6) << 15) + (c << 6) + (hn & 63)];  // wq[h][c][d]
  dst[idx] = f2b(v);
}

// dst[n][k] = src[k][n], src is (K,N) row-major
__global__ __launch_bounds__(256) void pack_T_k(const float* __restrict__ src,
                                                unsigned short* __restrict__ dst,
                                                int K, int N) {
  int idx = blockIdx.x * 256 + threadIdx.x;
  int n = idx / K, k = idx % K;
  dst[idx] = f2b(src[(long long)k * N + n]);
}

// ---------------- layernorm (wave per row, C=512), fp32 input ----------------
__global__ __launch_bounds__(256) void ln_k(const float* __restrict__ in,
                                            const float* __restrict__ g,
                                            const float* __restrict__ bb,
                                            unsigned short* __restrict__ out) {
  int row = blockIdx.x * 4 + (threadIdx.x >> 6);
  int lane = threadIdx.x & 63;
  const float* p = in + (size_t)row * 512 + lane * 8;
  f32x4 a = *(const f32x4*)p;
  f32x4 b = *(const f32x4*)(p + 4);
  float vals[8] = {a.x, a.y, a.z, a.w, b.x, b.y, b.z, b.w};
  float s = 0.f, q = 0.f;
#pragma unroll
  for (int i = 0; i < 8; i++) { s += vals[i]; q += vals[i] * vals[i]; }
#pragma unroll
  for (int off = 1; off < 64; off <<= 1) {
    s += __shfl_xor(s, off);
    q += __shfl_xor(q, off);
  }
  float mean = s * (1.0f / 512.0f);
  float rstd = rsqrtf(q * (1.0f / 512.0f) - mean * mean + 1e-5f);
  const float* gp = g + lane * 8;
  const float* bp = bb + lane * 8;
  s16x8 o;
#pragma unroll
  for (int i = 0; i < 8; i++) o[i] = (short)f2b((vals[i] - mean) * rstd * gp[i] + bp[i]);
  *(s16x8*)(out + (size_t)row * 512 + lane * 8) = o;
}

// ---------------- layernorm, bf16 input ----------------
__global__ __launch_bounds__(256) void ln_b_k(const unsigned short* __restrict__ in,
                                              const float* __restrict__ g,
                                              const float* __restrict__ bb,
                                              unsigned short* __restrict__ out) {
  int row = blockIdx.x * 4 + (threadIdx.x >> 6);
  int lane = threadIdx.x & 63;
  s16x8 v8 = *(const s16x8*)(in + (size_t)row * 512 + lane * 8);
  float vals[8];
#pragma unroll
  for (int i = 0; i < 8; i++) vals[i] = b2f((unsigned short)v8[i]);
  float s = 0.f, q = 0.f;
#pragma unroll
  for (int i = 0; i < 8; i++) { s += vals[i]; q += vals[i] * vals[i]; }
#pragma unroll
  for (int off = 1; off < 64; off <<= 1) {
    s += __shfl_xor(s, off);
    q += __shfl_xor(q, off);
  }
  float mean = s * (1.0f / 512.0f);
  float rstd = rsqrtf(q * (1.0f / 512.0f) - mean * mean + 1e-5f);
  const float* gp = g + lane * 8;
  const float* bp = bb + lane * 8;
  s16x8 o;
#pragma unroll
  for (int i = 0; i < 8; i++) o[i] = (short)f2b((vals[i] - mean) * rstd * gp[i] + bp[i]);
  *(s16x8*)(out + (size_t)row * 512 + lane * 8) = o;
}

// ---------------- attention (one wave per (b,h); T=16, D=64) ----------------
__global__ __launch_bounds__(256) void attn_k(const unsigned short* __restrict__ qkv,
                                              unsigned short* __restrict__ o) {
  int w = (blockIdx.x << 2) + (threadIdx.x >> 6);
  int lane = threadIdx.x & 63;
  int b = w >> 3, h = w & 7;
  int t = lane >> 2, p = lane & 3;   // 4 lanes per query row, 16 d's each

  size_t rowq = (size_t)(b * 16 + t) * 1536 + h * 64 + p * 16;
  float q[16];
  {
    s16x8 q0 = *(const s16x8*)(qkv + rowq);
    s16x8 q1 = *(const s16x8*)(qkv + rowq + 8);
#pragma unroll
    for (int i = 0; i < 8; i++) {
      q[i] = b2f((unsigned short)q0[i]) * 0.125f;
      q[8 + i] = b2f((unsigned short)q1[i]) * 0.125f;
    }
  }
  float lg[16];
  size_t kbase = (size_t)(b * 16) * 1536 + 512 + h * 64 + p * 16;
#pragma unroll
  for (int s = 0; s < 16; s++) {
    const unsigned short* kp = qkv + kbase + (size_t)s * 1536;
    s16x8 k0 = *(const s16x8*)kp;
    s16x8 k1 = *(const s16x8*)(kp + 8);
    float d = 0.f;
#pragma unroll
    for (int i = 0; i < 8; i++)
      d += q[i] * b2f((unsigned short)k0[i]) + q[8 + i] * b2f((unsigned short)k1[i]);
    d += __shfl_xor(d, 1);
    d += __shfl_xor(d, 2);
    lg[s] = d;
  }
  float mx = -1e30f;
#pragma unroll
  for (int s = 0; s < 16; s++)
    if (s <= t) mx = fmaxf(mx, lg[s]);
  float den = 0.f;
#pragma unroll
  for (int s = 0; s < 16; s++) {
    float e = (s <= t) ? __expf(lg[s] - mx) : 0.f;
    lg[s] = e;
    den += e;
  }
  float inv = 1.f / den;
  float acc[16] = {};
  size_t vbase = kbase + 512;
#pragma unroll
  for (int s = 0; s < 16; s++) {
    const unsigned short* vp = qkv + vbase + (size_t)s * 1536;
    s16x8 v0 = *(const s16x8*)vp;
    s16x8 v1 = *(const s16x8*)(vp + 8);
    float a = lg[s] * inv;
#pragma unroll
    for (int i = 0; i < 8; i++) {
      acc[i] += a * b2f((unsigned short)v0[i]);
      acc[8 + i] += a * b2f((unsigned short)v1[i]);
    }
  }
  size_t orow = (size_t)(b * 16 + t) * 512 + h * 64 + p * 16;
  s16x8 r0, r1;
#pragma unroll
  for (int i = 0; i < 8; i++) {
    r0[i] = (short)f2b(acc[i]);
    r1[i] = (short)f2b(acc[8 + i]);
  }
  *(s16x8*)(o + orow) = r0;
  *(s16x8*)(o + orow + 8) = r1;
}

// ------- bf16 MFMA GEMM: 256x256 tile, BK=32, 8 waves, 16-slot half-tile ring -------
// m201-cadence, race-free by construction. LDS = 16 slots x 8KB (one half-tile:
// 128 rows x 32 cols bf16). Tile t occupies slots (t&3)*4 + {A0,A1,B0,B1}.
// Per phase: {stage 2 halves | vmcnt(8) on even | BAR | ds_read 8/4 b128 |
// setprio(1) 16 MFMA setprio(0)}. Stage cadence: even phase of tile t stages
// B(t+2); odd stages A(t+3) -> lead 4-5 phases (~1000+cy > HBM latency); counted
// vmcnt(8) leaves exactly the 4 newest halves in flight; ring distance 16 halves
// puts every overwrite >= 2 barriers after its slot's last reader (both parities
// checked). ph1 ds_reads hoisted before the odd BAR (tile landed since even BAR).
// Source-side XOR swizzle (0 conflicts measured r2-r14).
enum { EPI_BF16 = 0, EPI_RESF32 = 1, EPI_RELU = 2, EPI_YBB = 3, EPI_OUTB = 4 };

template <int EPI>
__global__ __launch_bounds__(512) void gemm_bt(
    const unsigned short* __restrict__ A,   // (M, K) bf16
    const unsigned short* __restrict__ Bt,  // (N, K) bf16
    int K, int N, int nT,
    const float* __restrict__ bias, const void* __restrict__ res,
    float* __restrict__ outF, unsigned short* __restrict__ outB) {
  __shared__ __align__(16) unsigned char SM[131072];  // 16 x 8KB half-tile slots

  int tid = threadIdx.x;
  // XCD-chunked 1D swizzle, N-fastest tile order (grids are multiples of 8)
  int lid = ((int)blockIdx.x & 7) * ((int)gridDim.x >> 3) + ((int)blockIdx.x >> 3);
  int mBase = (lid / nT) * 256;
  int nBase = (lid % nT) * 256;

  int lane = tid & 63;
  int wid = tid >> 6;     // 0..7
  int wm = wid >> 2;      // 0..1 -> A half (rows wm*128..)
  int wn = wid & 3;       // 0..3 -> out cols wn*64..
  int l15 = lane & 15;
  int s4 = lane >> 4;
  int lr4 = s4 * 4;
  int fc = ((s4 ^ ((l15 >> 1) & 3)) << 3);   // swizzled 8-elem slot for ds_read

  // staging: thread covers row tid>>2 (0..127) of a half, 16B slot tid&3;
  // source col pre-swizzled: LDS[r][p] = G[r][p ^ ((r>>1)&3)]
  int srow = tid >> 2;
  int scol = (((tid & 3) ^ ((srow >> 1) & 3)) << 3);
  const unsigned short* pa = A + (size_t)(mBase + srow) * K + scol;
  const unsigned short* pb = Bt + (size_t)(nBase + srow) * K + scol;
  size_t k128 = (size_t)128 * K;
  unsigned short* dstB = (unsigned short*)SM + wid * 512;  // + slot*4096 shorts

  f32x4 acc[8][4] = {};

  auto stgA = [&](int slot, int a, int t) {   // A half a of tile t -> ring slot
    gl16(pa + (size_t)a * k128 + t * 32, dstB + slot * 4096);
  };
  auto stgB = [&](int slot, int b, int t) {
    gl16(pb + (size_t)b * k128 + t * 32, dstB + slot * 4096);
  };

  int NT = K >> 5;   // 16 or 64 here
  // prologue: A(0),B(0),A(1),B(1),A(2) in steady-state issue order (10 loads)
  stgA(0, 0, 0);  stgA(1, 1, 0);
  stgB(2, 0, 0);  stgB(3, 1, 0);
  stgA(4, 0, 1);  stgA(5, 1, 1);
  stgB(6, 0, 1);  stgB(7, 1, 1);
  stgA(8, 0, 2);  stgA(9, 1, 2);

  for (int t = 0; t < NT; ++t) {
    int sb = (t & 3) << 2;
    const unsigned short* hA = (const unsigned short*)SM + (size_t)(sb + wm) * 4096;
    const unsigned short* hB = (const unsigned short*)SM + (size_t)(sb + 2 + (wn >> 1)) * 4096;
    int br = (wn & 1) * 64;
    s16x8 af[4], bf[4];

    // ---------- even phase: stage B(t+2); gate tile t; B frags + A m0-3 ----------
    if (t + 2 < NT) {
      int s2 = ((t + 2) & 3) << 2;
      stgB(s2 + 2, 0, t + 2);
      stgB(s2 + 3, 1, t + 2);
      WAITV(8);      // 4 newest halves in flight; tile t fully landed
    } else if (t == NT - 2) {
      WAITV(4);      // only A(NT-1),B(NT-1) in flight
    } else {
      WAITV(0);      // last tile
    }
    BAR();           // collective: all waves' shares of tile t landed
#pragma unroll
    for (int n = 0; n < 4; ++n)
      bf[n] = *(const s16x8*)&hB[(br + n * 16 + l15) * 32 + fc];
#pragma unroll
    for (int m = 0; m < 4; ++m)
      af[m] = *(const s16x8*)&hA[(m * 16 + l15) * 32 + fc];
    __builtin_amdgcn_s_setprio(1);
#pragma unroll
    for (int m = 0; m < 4; ++m)
#pragma unroll
      for (int n = 0; n < 4; ++n)
        acc[m][n] = __builtin_amdgcn_mfma_f32_16x16x32_bf16(af[m], bf[n], acc[m][n], 0, 0, 0);
    __builtin_amdgcn_s_setprio(0);

    // ---------- odd phase: early A m4-7 reads; stage A(t+3); MFMA ----------
#pragma unroll
    for (int m = 0; m < 4; ++m)
      af[m] = *(const s16x8*)&hA[((m + 4) * 16 + l15) * 32 + fc];
    if (t + 3 < NT) {
      int s3 = ((t + 3) & 3) << 2;
      stgA(s3 + 0, 0, t + 3);
      stgA(s3 + 1, 1, t + 3);
    }
    BAR();           // phase alignment; protects ring reuse windows
    __builtin_amdgcn_s_setprio(1);
#pragma unroll
    for (int m = 0; m < 4; ++m)
#pragma unroll
      for (int n = 0; n < 4; ++n)
        acc[m + 4][n] = __builtin_amdgcn_mfma_f32_16x16x32_bf16(af[m], bf[n], acc[m + 4][n], 0, 0, 0);
    __builtin_amdgcn_s_setprio(0);
  }
  BAR();             // safe to reuse LDS for epilogue staging

  if (EPI == EPI_RESF32 || EPI == EPI_OUTB) {
    // fp32 output: direct stores are full 64B lines
#pragma unroll
    for (int n = 0; n < 4; n++) {
      int gc2 = nBase + wn * 64 + n * 16 + l15;
      float bv = bias[gc2];
#pragma unroll
      for (int m = 0; m < 8; m++) {
#pragma unroll
        for (int j = 0; j < 4; j++) {
          int gr = mBase + wm * 128 + m * 16 + lr4 + j;
          size_t off = (size_t)gr * N + gc2;
          float v = acc[m][n][j] + bv;
          if (EPI == EPI_RESF32)
            outF[off] = v + ((const float*)res)[off];
          else
            outF[off] = v + b2f(((const unsigned short*)res)[off]);
        }
      }
    }
  } else {
    // bf16 output: stage per-wave 16x64 fp32 in LDS, read back row-contiguous,
    // write short4 (16 lanes x 8B = 128B full-line runs per row)
    float* ep = (float*)SM + wid * 1088;   // 4352 B/wave, row stride 68 floats
    int colc = nBase + wn * 64 + l15 * 4;
    f32x4 bias4 = {0.f, 0.f, 0.f, 0.f};
    if (EPI != EPI_BF16) bias4 = *(const f32x4*)&bias[colc];
#pragma unroll
    for (int m = 0; m < 8; m++) {
#pragma unroll
      for (int n = 0; n < 4; n++)
#pragma unroll
        for (int j = 0; j < 4; j++)
          ep[(lr4 + j) * 68 + n * 16 + l15] = acc[m][n][j];
      WAITL();
#pragma unroll
      for (int rd = 0; rd < 4; rd++) {
        int r = s4 + 4 * rd;
        f32x4 v = *(const f32x4*)&ep[r * 68 + l15 * 4];
        v.x += bias4.x; v.y += bias4.y; v.z += bias4.z; v.w += bias4.w;
        int gr = mBase + wm * 128 + m * 16 + r;
        size_t off = (size_t)gr * N + colc;
        if (EPI == EPI_YBB) {
          s16x4 rb = *(const s16x4*)((const unsigned short*)res + off);
          v.x += b2f((unsigned short)rb[0]); v.y += b2f((unsigned short)rb[1]);
          v.z += b2f((unsigned short)rb[2]); v.w += b2f((unsigned short)rb[3]);
        } else if (EPI == EPI_RELU) {
          v.x = fmaxf(v.x, 0.f); v.y = fmaxf(v.y, 0.f);
          v.z = fmaxf(v.z, 0.f); v.w = fmaxf(v.w, 0.f);
        }
        s16x4 o;
        o[0] = (short)f2b(v.x); o[1] = (short)f2b(v.y);
        o[2] = (short)f2b(v.z); o[3] = (short)f2b(v.w);
        *(s16x4*)(outB + off) = o;
      }
      WAITL();  // reads of m done before m+1 overwrites (per-wave region)
    }
  }
}

// ---------------- launch ----------------
extern "C" void kernel_launch(void* const* d_in, const int* in_sizes, int n_in,
                              void* d_out, int out_size, void* d_ws, size_t ws_size,
                              hipStream_t stream) {
  const float* x      = (const float*)d_in[0];
  const float* ln1_g  = (const float*)d_in[1];
  const float* ln1_b  = (const float*)d_in[2];
  const float* wq     = (const float*)d_in[3];
  const float* wk     = (const float*)d_in[4];
  const float* wv     = (const float*)d_in[5];
  const float* w_proj = (const float*)d_in[6];
  const float* b_proj = (const float*)d_in[7];
  const float* ln2_g  = (const float*)d_in[8];
  const float* ln2_b  = (const float*)d_in[9];
  const float* w1     = (const float*)d_in[10];
  const float* b1     = (const float*)d_in[11];
  const float* w2     = (const float*)d_in[12];
  const float* b2     = (const float*)d_in[13];
  float* out = (float*)d_out;

  char* ws = (char*)d_ws;
  unsigned short* qkvT  = (unsigned short*)(ws + 0);          // 1.5 MB
  unsigned short* projT = (unsigned short*)(ws + 1572864);    // 0.5 MB
  unsigned short* w1T   = (unsigned short*)(ws + 2097152);    // 2 MB
  unsigned short* w2T   = (unsigned short*)(ws + 4194304);    // 2 MB
  unsigned short* hbuf  = (unsigned short*)(ws + 6291456);    // 67 MB (h, then h2)
  unsigned short* qkv   = (unsigned short*)(ws + 73400320);   // 201 MB of 268 MB region (ff)
  unsigned short* xb    = (unsigned short*)(ws + 274726912);  // 67 MB spare in ff region
  unsigned short* obuf  = (unsigned short*)(ws + 341835776);  // 67 MB
  unsigned short* ybuf  = (unsigned short*)(ws + 408944640);  // 67 MB (bf16 y) if room
  bool yb16 = ws_size >= 476053504ull;

  pack_qkv_k<<<3072, 256, 0, stream>>>(wq, wk, wv, qkvT);
  pack_T_k<<<1024, 256, 0, stream>>>(w_proj, projT, 512, 512);
  pack_T_k<<<4096, 256, 0, stream>>>(w1, w1T, 512, 2048);
  pack_T_k<<<4096, 256, 0, stream>>>(w2, w2T, 2048, 512);

  unsigned short* ff = qkv;  // ff (268 MB) overlays qkv+xb after both are dead
  if (yb16) {
    pack_x_k<<<16384, 256, 0, stream>>>(x, xb);         // x -> bf16 once
    ln_b_k<<<16384, 256, 0, stream>>>(xb, ln1_g, ln1_b, hbuf);
    // qkv = h @ [wq|wk|wv]  (M=65536, K=512, N=1536): 256 m x 6 n = 1536
    gemm_bt<EPI_BF16><<<1536, 512, 0, stream>>>(hbuf, qkvT, 512, 1536, 6,
                                                nullptr, nullptr, nullptr, qkv);
    attn_k<<<8192, 256, 0, stream>>>(qkv, obuf);
    // y(bf16) = o @ w_proj + b_proj + xb
    gemm_bt<EPI_YBB><<<512, 512, 0, stream>>>(obuf, projT, 512, 512, 2,
                                              b_proj, xb, nullptr, ybuf);
    ln_b_k<<<16384, 256, 0, stream>>>(ybuf, ln2_g, ln2_b, hbuf);
    // ff = relu(h2 @ w1 + b1)  — overwrites qkv AND xb region (both dead)
    gemm_bt<EPI_RELU><<<2048, 512, 0, stream>>>(hbuf, w1T, 512, 2048, 8,
                                                b1, nullptr, nullptr, ff);
    // out(f32) = ff @ w2 + b2 + y(bf16)
    gemm_bt<EPI_OUTB><<<512, 512, 0, stream>>>(ff, w2T, 2048, 512, 2,
                                               b2, ybuf, out, nullptr);
  } else {
    // fallback: y fp32 in d_out, no xb
    ln_k<<<16384, 256, 0, stream>>>(x, ln1_g, ln1_b, hbuf);
    gemm_bt<EPI_BF16><<<1536, 512, 0, stream>>>(hbuf, qkvT, 512, 1536, 6,
                                                nullptr, nullptr, nullptr, qkv);
    attn_k<<<8192, 256, 0, stream>>>(qkv, obuf);
    gemm_bt<EPI_RESF32><<<512, 512, 0, stream>>>(obuf, projT, 512, 512, 2,
                                                 b_proj, x, out, nullptr);
    ln_k<<<16384, 256, 0, stream>>>(out, ln2_g, ln2_b, hbuf);
    gemm_bt<EPI_RELU><<<2048, 512, 0, stream>>>(hbuf, w1T, 512, 2048, 8,
                                                b1, nullptr, nullptr, ff);
    gemm_bt<EPI_RESF32><<<512, 512, 0, stream>>>(ff, w2T, 2048, 512, 2,
                                                 b2, out, out, nullptr);
  }
}

// Round 16
// 759.671 us; speedup vs baseline: 1.2032x; 1.0009x over previous
//
#include <hip/hip_runtime.h>
#include <hip/hip_bf16.h>

typedef __attribute__((ext_vector_type(8))) short s16x8;
typedef __attribute__((ext_vector_type(4))) short s16x4;
typedef __attribute__((ext_vector_type(4))) float f32x4;

#define GAS __attribute__((address_space(1)))
#define LAS __attribute__((address_space(3)))

#define WAITV(N) asm volatile("s_waitcnt vmcnt(" #N ")" ::: "memory")
#define WAITL() asm volatile("s_waitcnt lgkmcnt(0)" ::: "memory")
#define BAR() __builtin_amdgcn_s_barrier()

__device__ __forceinline__ float b2f(unsigned short u) {
  union { unsigned int i; float f; } x; x.i = ((unsigned int)u) << 16; return x.f;
}
__device__ __forceinline__ unsigned short f2b(float f) {
  union { float f; unsigned int i; } x; x.f = f;
  unsigned int r = x.i + 0x7fffu + ((x.i >> 16) & 1u);
  return (unsigned short)(r >> 16);
}

// async global->LDS, 16B per lane; lds dest is wave-uniform base + lane*16
__device__ __forceinline__ void gl16(const unsigned short* g, unsigned short* l) {
  __builtin_amdgcn_global_load_lds((const GAS unsigned int*)g,
                                   (LAS unsigned int*)l, 16, 0, 0);
}

// ---------------- packing ----------------
__global__ __launch_bounds__(256) void pack_x_k(const float* __restrict__ x,
                                                unsigned short* __restrict__ xb) {
  size_t i = ((size_t)blockIdx.x * 256 + threadIdx.x) * 8;
  f32x4 a = *(const f32x4*)(x + i);
  f32x4 b = *(const f32x4*)(x + i + 4);
  float vals[8] = {a.x, a.y, a.z, a.w, b.x, b.y, b.z, b.w};
  s16x8 o;
#pragma unroll
  for (int k = 0; k < 8; k++) o[k] = (short)f2b(vals[k]);
  *(s16x8*)(xb + i) = o;
}

__global__ __launch_bounds__(256) void pack_qkv_k(const float* __restrict__ wq,
                                                  const float* __restrict__ wk,
                                                  const float* __restrict__ wv,
                                                  unsigned short* __restrict__ dst) {
  int idx = blockIdx.x * 256 + threadIdx.x;   // n*512 + c
  int n = idx >> 9, c = idx & 511;
  int sel = n >> 9;
  int hn = n & 511;
  const float* src = sel == 0 ? wq : (sel == 1 ? wk : wv);
  float v = src[((hn >> 6) << 15) + (c << 6) + (hn & 63)];  // wq[h][c][d]
  dst[idx] = f2b(v);
}

// dst[n][k] = src[k][n], src is (K,N) row-major
__global__ __launch_bounds__(256) void pack_T_k(const float* __restrict__ src,
                                                unsigned short* __restrict__ dst,
                                                int K, int N) {
  int idx = blockIdx.x * 256 + threadIdx.x;
  int n = idx / K, k = idx % K;
  dst[idx] = f2b(src[(long long)k * N + n]);
}

// ---------------- layernorm (wave per row, C=512), fp32 input ----------------
__global__ __launch_bounds__(256) void ln_k(const float* __restrict__ in,
                                            const float* __restrict__ g,
                                            const float* __restrict__ bb,
                                            unsigned short* __restrict__ out) {
  int row = blockIdx.x * 4 + (threadIdx.x >> 6);
  int lane = threadIdx.x & 63;
  const float* p = in + (size_t)row * 512 + lane * 8;
  f32x4 a = *(const f32x4*)p;
  f32x4 b = *(const f32x4*)(p + 4);
  float vals[8] = {a.x, a.y, a.z, a.w, b.x, b.y, b.z, b.w};
  float s = 0.f, q = 0.f;
#pragma unroll
  for (int i = 0; i < 8; i++) { s += vals[i]; q += vals[i] * vals[i]; }
#pragma unroll
  for (int off = 1; off < 64; off <<= 1) {
    s += __shfl_xor(s, off);
    q += __shfl_xor(q, off);
  }
  float mean = s * (1.0f / 512.0f);
  float rstd = rsqrtf(q * (1.0f / 512.0f) - mean * mean + 1e-5f);
  const float* gp = g + lane * 8;
  const float* bp = bb + lane * 8;
  s16x8 o;
#pragma unroll
  for (int i = 0; i < 8; i++) o[i] = (short)f2b((vals[i] - mean) * rstd * gp[i] + bp[i]);
  *(s16x8*)(out + (size_t)row * 512 + lane * 8) = o;
}

// ---------------- layernorm, bf16 input ----------------
__global__ __launch_bounds__(256) void ln_b_k(const unsigned short* __restrict__ in,
                                              const float* __restrict__ g,
                                              const float* __restrict__ bb,
                                              unsigned short* __restrict__ out) {
  int row = blockIdx.x * 4 + (threadIdx.x >> 6);
  int lane = threadIdx.x & 63;
  s16x8 v8 = *(const s16x8*)(in + (size_t)row * 512 + lane * 8);
  float vals[8];
#pragma unroll
  for (int i = 0; i < 8; i++) vals[i] = b2f((unsigned short)v8[i]);
  float s = 0.f, q = 0.f;
#pragma unroll
  for (int i = 0; i < 8; i++) { s += vals[i]; q += vals[i] * vals[i]; }
#pragma unroll
  for (int off = 1; off < 64; off <<= 1) {
    s += __shfl_xor(s, off);
    q += __shfl_xor(q, off);
  }
  float mean = s * (1.0f / 512.0f);
  float rstd = rsqrtf(q * (1.0f / 512.0f) - mean * mean + 1e-5f);
  const float* gp = g + lane * 8;
  const float* bp = bb + lane * 8;
  s16x8 o;
#pragma unroll
  for (int i = 0; i < 8; i++) o[i] = (short)f2b((vals[i] - mean) * rstd * gp[i] + bp[i]);
  *(s16x8*)(out + (size_t)row * 512 + lane * 8) = o;
}

// ---------------- attention (one wave per (b,h); T=16, D=64) ----------------
__global__ __launch_bounds__(256) void attn_k(const unsigned short* __restrict__ qkv,
                                              unsigned short* __restrict__ o) {
  int w = (blockIdx.x << 2) + (threadIdx.x >> 6);
  int lane = threadIdx.x & 63;
  int b = w >> 3, h = w & 7;
  int t = lane >> 2, p = lane & 3;   // 4 lanes per query row, 16 d's each

  size_t rowq = (size_t)(b * 16 + t) * 1536 + h * 64 + p * 16;
  float q[16];
  {
    s16x8 q0 = *(const s16x8*)(qkv + rowq);
    s16x8 q1 = *(const s16x8*)(qkv + rowq + 8);
#pragma unroll
    for (int i = 0; i < 8; i++) {
      q[i] = b2f((unsigned short)q0[i]) * 0.125f;
      q[8 + i] = b2f((unsigned short)q1[i]) * 0.125f;
    }
  }
  float lg[16];
  size_t kbase = (size_t)(b * 16) * 1536 + 512 + h * 64 + p * 16;
#pragma unroll
  for (int s = 0; s < 16; s++) {
    const unsigned short* kp = qkv + kbase + (size_t)s * 1536;
    s16x8 k0 = *(const s16x8*)kp;
    s16x8 k1 = *(const s16x8*)(kp + 8);
    float d = 0.f;
#pragma unroll
    for (int i = 0; i < 8; i++)
      d += q[i] * b2f((unsigned short)k0[i]) + q[8 + i] * b2f((unsigned short)k1[i]);
    d += __shfl_xor(d, 1);
    d += __shfl_xor(d, 2);
    lg[s] = d;
  }
  float mx = -1e30f;
#pragma unroll
  for (int s = 0; s < 16; s++)
    if (s <= t) mx = fmaxf(mx, lg[s]);
  float den = 0.f;
#pragma unroll
  for (int s = 0; s < 16; s++) {
    float e = (s <= t) ? __expf(lg[s] - mx) : 0.f;
    lg[s] = e;
    den += e;
  }
  float inv = 1.f / den;
  float acc[16] = {};
  size_t vbase = kbase + 512;
#pragma unroll
  for (int s = 0; s < 16; s++) {
    const unsigned short* vp = qkv + vbase + (size_t)s * 1536;
    s16x8 v0 = *(const s16x8*)vp;
    s16x8 v1 = *(const s16x8*)(vp + 8);
    float a = lg[s] * inv;
#pragma unroll
    for (int i = 0; i < 8; i++) {
      acc[i] += a * b2f((unsigned short)v0[i]);
      acc[8 + i] += a * b2f((unsigned short)v1[i]);
    }
  }
  size_t orow = (size_t)(b * 16 + t) * 512 + h * 64 + p * 16;
  s16x8 r0, r1;
#pragma unroll
  for (int i = 0; i < 8; i++) {
    r0[i] = (short)f2b(acc[i]);
    r1[i] = (short)f2b(acc[8 + i]);
  }
  *(s16x8*)(o + orow) = r0;
  *(s16x8*)(o + orow + 8) = r1;
}

// ------- bf16 MFMA GEMM: 256x256 tile, BK=32, 8 waves, 16-slot half-tile ring -------
// m201-cadence, race-free by construction. LDS = 16 slots x 8KB (one half-tile:
// 128 rows x 32 cols bf16). Tile t occupies slots (t&3)*4 + {A0,A1,B0,B1}.
// Per phase: {stage 2 halves | vmcnt(8) on even | BAR | ds_read 8/4 b128 |
// setprio(1) 16 MFMA setprio(0)}. Stage cadence: even phase of tile t stages
// B(t+2); odd stages A(t+3) -> lead 4-5 phases (~1000+cy > HBM latency); counted
// vmcnt(8) leaves exactly the 4 newest halves in flight; ring distance 16 halves
// puts every overwrite >= 2 barriers after its slot's last reader (both parities
// checked). ph1 ds_reads hoisted before the odd BAR (tile landed since even BAR).
// Source-side XOR swizzle (0 conflicts measured r2-r14).
enum { EPI_BF16 = 0, EPI_RESF32 = 1, EPI_RELU = 2, EPI_YBB = 3, EPI_OUTB = 4 };

template <int EPI>
__global__ __launch_bounds__(512) void gemm_bt(
    const unsigned short* __restrict__ A,   // (M, K) bf16
    const unsigned short* __restrict__ Bt,  // (N, K) bf16
    int K, int N, int nT,
    const float* __restrict__ bias, const void* __restrict__ res,
    float* __restrict__ outF, unsigned short* __restrict__ outB) {
  __shared__ __align__(16) unsigned char SM[131072];  // 16 x 8KB half-tile slots

  int tid = threadIdx.x;
  // XCD-chunked 1D swizzle, N-fastest tile order (grids are multiples of 8)
  int lid = ((int)blockIdx.x & 7) * ((int)gridDim.x >> 3) + ((int)blockIdx.x >> 3);
  int mBase = (lid / nT) * 256;
  int nBase = (lid % nT) * 256;

  int lane = tid & 63;
  int wid = tid >> 6;     // 0..7
  int wm = wid >> 2;      // 0..1 -> A half (rows wm*128..)
  int wn = wid & 3;       // 0..3 -> out cols wn*64..
  int l15 = lane & 15;
  int s4 = lane >> 4;
  int lr4 = s4 * 4;
  int fc = ((s4 ^ ((l15 >> 1) & 3)) << 3);   // swizzled 8-elem slot for ds_read

  // staging: thread covers row tid>>2 (0..127) of a half, 16B slot tid&3;
  // source col pre-swizzled: LDS[r][p] = G[r][p ^ ((r>>1)&3)]
  int srow = tid >> 2;
  int scol = (((tid & 3) ^ ((srow >> 1) & 3)) << 3);
  const unsigned short* pa = A + (size_t)(mBase + srow) * K + scol;
  const unsigned short* pb = Bt + (size_t)(nBase + srow) * K + scol;
  size_t k128 = (size_t)128 * K;
  unsigned short* dstB = (unsigned short*)SM + wid * 512;  // + slot*4096 shorts

  f32x4 acc[8][4] = {};

  auto stgA = [&](int slot, int a, int t) {   // A half a of tile t -> ring slot
    gl16(pa + (size_t)a * k128 + t * 32, dstB + slot * 4096);
  };
  auto stgB = [&](int slot, int b, int t) {
    gl16(pb + (size_t)b * k128 + t * 32, dstB + slot * 4096);
  };

  int NT = K >> 5;   // 16 or 64 here
  // prologue: A(0),B(0),A(1),B(1),A(2) in steady-state issue order (10 loads)
  stgA(0, 0, 0);  stgA(1, 1, 0);
  stgB(2, 0, 0);  stgB(3, 1, 0);
  stgA(4, 0, 1);  stgA(5, 1, 1);
  stgB(6, 0, 1);  stgB(7, 1, 1);
  stgA(8, 0, 2);  stgA(9, 1, 2);

  for (int t = 0; t < NT; ++t) {
    int sb = (t & 3) << 2;
    const unsigned short* hA = (const unsigned short*)SM + (size_t)(sb + wm) * 4096;
    const unsigned short* hB = (const unsigned short*)SM + (size_t)(sb + 2 + (wn >> 1)) * 4096;
    int br = (wn & 1) * 64;
    s16x8 af[4], bf[4];

    // ---------- even phase: stage B(t+2); gate tile t; B frags + A m0-3 ----------
    if (t + 2 < NT) {
      int s2 = ((t + 2) & 3) << 2;
      stgB(s2 + 2, 0, t + 2);
      stgB(s2 + 3, 1, t + 2);
      WAITV(8);      // 4 newest halves in flight; tile t fully landed
    } else if (t == NT - 2) {
      WAITV(4);      // only A(NT-1),B(NT-1) in flight
    } else {
      WAITV(0);      // last tile
    }
    BAR();           // collective: all waves' shares of tile t landed
#pragma unroll
    for (int n = 0; n < 4; ++n)
      bf[n] = *(const s16x8*)&hB[(br + n * 16 + l15) * 32 + fc];
#pragma unroll
    for (int m = 0; m < 4; ++m)
      af[m] = *(const s16x8*)&hA[(m * 16 + l15) * 32 + fc];
    __builtin_amdgcn_s_setprio(1);
#pragma unroll
    for (int m = 0; m < 4; ++m)
#pragma unroll
      for (int n = 0; n < 4; ++n)
        acc[m][n] = __builtin_amdgcn_mfma_f32_16x16x32_bf16(af[m], bf[n], acc[m][n], 0, 0, 0);
    __builtin_amdgcn_s_setprio(0);

    // ---------- odd phase: early A m4-7 reads; stage A(t+3); MFMA ----------
#pragma unroll
    for (int m = 0; m < 4; ++m)
      af[m] = *(const s16x8*)&hA[((m + 4) * 16 + l15) * 32 + fc];
    if (t + 3 < NT) {
      int s3 = ((t + 3) & 3) << 2;
      stgA(s3 + 0, 0, t + 3);
      stgA(s3 + 1, 1, t + 3);
    }
    BAR();           // phase alignment; protects ring reuse windows
    __builtin_amdgcn_s_setprio(1);
#pragma unroll
    for (int m = 0; m < 4; ++m)
#pragma unroll
      for (int n = 0; n < 4; ++n)
        acc[m + 4][n] = __builtin_amdgcn_mfma_f32_16x16x32_bf16(af[m], bf[n], acc[m + 4][n], 0, 0, 0);
    __builtin_amdgcn_s_setprio(0);
  }
  BAR();             // safe to reuse LDS for epilogue staging

  if (EPI == EPI_RESF32 || EPI == EPI_OUTB) {
    // fp32 output: direct stores are full 64B lines
#pragma unroll
    for (int n = 0; n < 4; n++) {
      int gc2 = nBase + wn * 64 + n * 16 + l15;
      float bv = bias[gc2];
#pragma unroll
      for (int m = 0; m < 8; m++) {
#pragma unroll
        for (int j = 0; j < 4; j++) {
          int gr = mBase + wm * 128 + m * 16 + lr4 + j;
          size_t off = (size_t)gr * N + gc2;
          float v = acc[m][n][j] + bv;
          if (EPI == EPI_RESF32)
            outF[off] = v + ((const float*)res)[off];
          else
            outF[off] = v + b2f(((const unsigned short*)res)[off]);
        }
      }
    }
  } else {
    // bf16 output: stage per-wave 16x64 fp32 in LDS, read back row-contiguous,
    // write short4 (16 lanes x 8B = 128B full-line runs per row)
    float* ep = (float*)SM + wid * 1088;   // 4352 B/wave, row stride 68 floats
    int colc = nBase + wn * 64 + l15 * 4;
    f32x4 bias4 = {0.f, 0.f, 0.f, 0.f};
    if (EPI != EPI_BF16) bias4 = *(const f32x4*)&bias[colc];
#pragma unroll
    for (int m = 0; m < 8; m++) {
#pragma unroll
      for (int n = 0; n < 4; n++)
#pragma unroll
        for (int j = 0; j < 4; j++)
          ep[(lr4 + j) * 68 + n * 16 + l15] = acc[m][n][j];
      WAITL();
#pragma unroll
      for (int rd = 0; rd < 4; rd++) {
        int r = s4 + 4 * rd;
        f32x4 v = *(const f32x4*)&ep[r * 68 + l15 * 4];
        v.x += bias4.x; v.y += bias4.y; v.z += bias4.z; v.w += bias4.w;
        int gr = mBase + wm * 128 + m * 16 + r;
        size_t off = (size_t)gr * N + colc;
        if (EPI == EPI_YBB) {
          s16x4 rb = *(const s16x4*)((const unsigned short*)res + off);
          v.x += b2f((unsigned short)rb[0]); v.y += b2f((unsigned short)rb[1]);
          v.z += b2f((unsigned short)rb[2]); v.w += b2f((unsigned short)rb[3]);
        } else if (EPI == EPI_RELU) {
          v.x = fmaxf(v.x, 0.f); v.y = fmaxf(v.y, 0.f);
          v.z = fmaxf(v.z, 0.f); v.w = fmaxf(v.w, 0.f);
        }
        s16x4 o;
        o[0] = (short)f2b(v.x); o[1] = (short)f2b(v.y);
        o[2] = (short)f2b(v.z); o[3] = (short)f2b(v.w);
        *(s16x4*)(outB + off) = o;
      }
      WAITL();  // reads of m done before m+1 overwrites (per-wave region)
    }
  }
}

// ---------------- launch ----------------
extern "C" void kernel_launch(void* const* d_in, const int* in_sizes, int n_in,
                              void* d_out, int out_size, void* d_ws, size_t ws_size,
                              hipStream_t stream) {
  const float* x      = (const float*)d_in[0];
  const float* ln1_g  = (const float*)d_in[1];
  const float* ln1_b  = (const float*)d_in[2];
  const float* wq     = (const float*)d_in[3];
  const float* wk     = (const float*)d_in[4];
  const float* wv     = (const float*)d_in[5];
  const float* w_proj = (const float*)d_in[6];
  const float* b_proj = (const float*)d_in[7];
  const float* ln2_g  = (const float*)d_in[8];
  const float* ln2_b  = (const float*)d_in[9];
  const float* w1     = (const float*)d_in[10];
  const float* b1     = (const float*)d_in[11];
  const float* w2     = (const float*)d_in[12];
  const float* b2     = (const float*)d_in[13];
  float* out = (float*)d_out;

  char* ws = (char*)d_ws;
  unsigned short* qkvT  = (unsigned short*)(ws + 0);          // 1.5 MB
  unsigned short* projT = (unsigned short*)(ws + 1572864);    // 0.5 MB
  unsigned short* w1T   = (unsigned short*)(ws + 2097152);    // 2 MB
  unsigned short* w2T   = (unsigned short*)(ws + 4194304);    // 2 MB
  unsigned short* hbuf  = (unsigned short*)(ws + 6291456);    // 67 MB (h, then h2)
  unsigned short* qkv   = (unsigned short*)(ws + 73400320);   // 201 MB of 268 MB region (ff)
  unsigned short* xb    = (unsigned short*)(ws + 274726912);  // 67 MB spare in ff region
  unsigned short* obuf  = (unsigned short*)(ws + 341835776);  // 67 MB
  unsigned short* ybuf  = (unsigned short*)(ws + 408944640);  // 67 MB (bf16 y) if room
  bool yb16 = ws_size >= 476053504ull;

  pack_qkv_k<<<3072, 256, 0, stream>>>(wq, wk, wv, qkvT);
  pack_T_k<<<1024, 256, 0, stream>>>(w_proj, projT, 512, 512);
  pack_T_k<<<4096, 256, 0, stream>>>(w1, w1T, 512, 2048);
  pack_T_k<<<4096, 256, 0, stream>>>(w2, w2T, 2048, 512);

  unsigned short* ff = qkv;  // ff (268 MB) overlays qkv+xb after both are dead
  if (yb16) {
    pack_x_k<<<16384, 256, 0, stream>>>(x, xb);         // x -> bf16 once
    ln_b_k<<<16384, 256, 0, stream>>>(xb, ln1_g, ln1_b, hbuf);
    // qkv = h @ [wq|wk|wv]  (M=65536, K=512, N=1536): 256 m x 6 n = 1536
    gemm_bt<EPI_BF16><<<1536, 512, 0, stream>>>(hbuf, qkvT, 512, 1536, 6,
                                                nullptr, nullptr, nullptr, qkv);
    attn_k<<<8192, 256, 0, stream>>>(qkv, obuf);
    // y(bf16) = o @ w_proj + b_proj + xb
    gemm_bt<EPI_YBB><<<512, 512, 0, stream>>>(obuf, projT, 512, 512, 2,
                                              b_proj, xb, nullptr, ybuf);
    ln_b_k<<<16384, 256, 0, stream>>>(ybuf, ln2_g, ln2_b, hbuf);
    // ff = relu(h2 @ w1 + b1)  — overwrites qkv AND xb region (both dead)
    gemm_bt<EPI_RELU><<<2048, 512, 0, stream>>>(hbuf, w1T, 512, 2048, 8,
                                                b1, nullptr, nullptr, ff);
    // out(f32) = ff @ w2 + b2 + y(bf16)
    gemm_bt<EPI_OUTB><<<512, 512, 0, stream>>>(ff, w2T, 2048, 512, 2,
                                               b2, ybuf, out, nullptr);
  } else {
    // fallback: y fp32 in d_out, no xb
    ln_k<<<16384, 256, 0, stream>>>(x, ln1_g, ln1_b, hbuf);
    gemm_bt<EPI_BF16><<<1536, 512, 0, stream>>>(hbuf, qkvT, 512, 1536, 6,
                                                nullptr, nullptr, nullptr, qkv);
    attn_k<<<8192, 256, 0, stream>>>(qkv, obuf);
    gemm_bt<EPI_RESF32><<<512, 512, 0, stream>>>(obuf, projT, 512, 512, 2,
                                                 b_proj, x, out, nullptr);
    ln_k<<<16384, 256, 0, stream>>>(out, ln2_g, ln2_b, hbuf);
    gemm_bt<EPI_RELU><<<2048, 512, 0, stream>>>(hbuf, w1T, 512, 2048, 8,
                                                b1, nullptr, nullptr, ff);
    gemm_bt<EPI_RESF32><<<512, 512, 0, stream>>>(ff, w2T, 2048, 512, 2,
                                                 b2, out, out, nullptr);
  }
}